// Round 16
// baseline (250.954 us; speedup 1.0000x reference)
//
#include <hip/hip_runtime.h>
#include <hip/hip_cooperative_groups.h>
#include <math.h>

namespace cg = cooperative_groups;

#define DIM 128
#define NHEADS 16
#define DPH 8
#define NATOMS 50000
#define NEDGES 400000
#define LN_EPS 1e-5f

typedef float f32x4 __attribute__((ext_vector_type(4)));
typedef short s16x8 __attribute__((ext_vector_type(8)));

static __device__ __forceinline__ unsigned short f2bf(float f) {
  unsigned u = __builtin_bit_cast(unsigned, f);
  unsigned r = (u + 0x7FFFu + ((u >> 16) & 1u)) >> 16;  // RNE
  return (unsigned short)r;
}
static __device__ __forceinline__ unsigned packbf(float lo, float hi) {
  return (unsigned)f2bf(lo) | ((unsigned)f2bf(hi) << 16);
}
static __device__ __forceinline__ float bflo(unsigned u) {
  return __builtin_bit_cast(float, u << 16);
}
static __device__ __forceinline__ float bfhi(unsigned u) {
  return __builtin_bit_cast(float, u & 0xffff0000u);
}

// fast GELU (tanh form): x * sigmoid(2*c0*(x + c1*x^3))
static __device__ __forceinline__ float gelu_fast(float x) {
  const float c0 = 0.7978845608028654f;
  const float c1 = 0.044715f;
  float u = c0 * (x + c1 * x * x * x);
  return __fdividef(x, 1.0f + __expf(-2.0f * u));
}

#define HIST4_NB ((NEDGES / 4 + 255) / 256)  // 391
#define SCAT_NB ((NEDGES + 255) / 256)       // 1563
#define SCAN_NB 196                          // ceil(50000/256)
#define LN_NB (NATOMS / 16)                  // 3125

// ---------------------------------------------------------------------------
// k_prep: weight convert/transpose + cnt zeroing.
// ---------------------------------------------------------------------------
__global__ __launch_bounds__(256) void k_prep(
    const float* __restrict__ qkv_w, const float* __restrict__ out_w,
    unsigned short* __restrict__ wTq, unsigned short* __restrict__ wTo,
    int* __restrict__ cnt)
{
  const int idx = blockIdx.x * 256 + threadIdx.x;
  if (idx < NATOMS) cnt[idx] = 0;
  if (idx < 384 * 128) {
    const int c = idx >> 7, k = idx & 127;
    wTq[idx] = f2bf(qkv_w[k * 384 + c]);
  } else {
    const int i2 = idx - 384 * 128;
    const int c = i2 >> 7, k = i2 & 127;
    wTo[i2] = f2bf(out_w[k * 128 + c]);
  }
}

// ---------------------------------------------------------------------------
// k_csr_build: COOPERATIVE fused hist4 + scan1 + scan23.
// 196 blocks x 256 (co-resident). Phase H: int4 histogram, block-strided
// over 391 tiles. grid.sync. Phase S1: per-block inclusive scan -> locx
// (exclusive) + psum[bid]. grid.sync. Phase S23: block offset over psum +
// apply -> base/cursor. Replaces 3 dispatches (2 launch gaps removed).
// ---------------------------------------------------------------------------
__global__ __launch_bounds__(256) void k_csr_build(
    const int4* __restrict__ row4, int* __restrict__ cnt,
    int* __restrict__ locx, int* __restrict__ psum,
    int* __restrict__ base, int* __restrict__ cursor)
{
  cg::grid_group grid = cg::this_grid();
  const int tid = threadIdx.x;
  const int bid = blockIdx.x;

  // phase H: histogram (block-strided)
  for (int tile = bid; tile < HIST4_NB; tile += SCAN_NB) {
    const int e4 = tile * 256 + tid;
    if (e4 < NEDGES / 4) {
      const int4 r = row4[e4];
      atomicAdd(&cnt[r.x], 1);
      atomicAdd(&cnt[r.y], 1);
      atomicAdd(&cnt[r.z], 1);
      atomicAdd(&cnt[r.w], 1);
    }
  }
  grid.sync();

  // phase S1: per-block scan
  __shared__ int sh[256];
  const int i = bid * 256 + tid;
  const int v = (i < NATOMS) ? cnt[i] : 0;
  sh[tid] = v;
  __syncthreads();
  #pragma unroll
  for (int off = 1; off < 256; off <<= 1) {
    const int cur = sh[tid];
    const int add = (tid >= off) ? sh[tid - off] : 0;
    __syncthreads();
    sh[tid] = cur + add;
    __syncthreads();
  }
  if (i < NATOMS) locx[i] = sh[tid] - v;  // exclusive
  if (tid == 255) psum[bid] = sh[255];
  grid.sync();

  // phase S23: exclusive offset over psum + apply
  __shared__ int ws[4];
  const int lane = tid & 63;
  const int wid = tid >> 6;
  int s = (tid < bid) ? psum[tid] : 0;  // bid <= 195 < 256
  #pragma unroll
  for (int m = 1; m < 64; m <<= 1) s += __shfl_xor(s, m);
  if (lane == 0) ws[wid] = s;
  __syncthreads();
  const int off = ws[0] + ws[1] + ws[2] + ws[3];

  if (i < NATOMS) {
    const int b = locx[i] + off;
    base[i] = b;
    cursor[i] = b;
  }
  if (bid == 0 && tid == 0) base[NATOMS] = NEDGES;
}

// ---------------------------------------------------------------------------
// k_scatter_ln: FUSED grid. Blocks [0, SCAT_NB): scatter edge descriptors
// into CSR order (descA[p]={e,col,radial,ev0}, descB[p]={ev1,ev2}). Blocks
// [SCAT_NB, SCAT_NB+LN_NB): LayerNorm + QKV projection (MFMA), packed bf16
// outputs. Independent workloads co-schedule across CUs.
// ---------------------------------------------------------------------------
__global__ __launch_bounds__(256) void k_scatter_ln(
    const int* __restrict__ row, const int* __restrict__ col,
    const float* __restrict__ radial, const float* __restrict__ evec,
    int* __restrict__ cursor, int4* __restrict__ descA,
    float2* __restrict__ descB,
    const float* __restrict__ node, const unsigned short* __restrict__ wTq,
    const float* __restrict__ bias, const float* __restrict__ g,
    const float* __restrict__ beta, unsigned* __restrict__ qb,
    unsigned* __restrict__ kvb)
{
  if (blockIdx.x < SCAT_NB) {
    const int e = blockIdx.x * 256 + threadIdx.x;
    if (e < NEDGES) {
      const int p = atomicAdd(&cursor[row[e]], 1);
      descA[p] = make_int4(e, col[e], __float_as_int(radial[e]),
                           __float_as_int(evec[(size_t)e * 3]));
      descB[p] = make_float2(evec[(size_t)e * 3 + 1], evec[(size_t)e * 3 + 2]);
    }
    return;
  }

  __shared__ float hpad[16][132];
  __shared__ float so[16][388];
  const int a0 = (blockIdx.x - SCAT_NB) * 16;
  const int tid = threadIdx.x;
  const int wid = tid >> 6;
  const int lane = tid & 63;

  for (int j = 0; j < 4; ++j) {
    const int a = wid * 4 + j;
    const float x0 = node[(size_t)(a0 + a) * DIM + lane];
    const float x1 = node[(size_t)(a0 + a) * DIM + 64 + lane];
    float s = x0 + x1;
    #pragma unroll
    for (int m = 1; m < 64; m <<= 1) s += __shfl_xor(s, m);
    const float mu = s * (1.0f / 128.0f);
    const float d0 = x0 - mu, d1 = x1 - mu;
    float v = d0 * d0 + d1 * d1;
    #pragma unroll
    for (int m = 1; m < 64; m <<= 1) v += __shfl_xor(v, m);
    const float rs = rsqrtf(v * (1.0f / 128.0f) + LN_EPS);
    hpad[a][lane]      = d0 * rs * g[lane]      + beta[lane];
    hpad[a][64 + lane] = d1 * rs * g[64 + lane] + beta[64 + lane];
  }
  __syncthreads();

  const int lrow = lane & 15;
  const int lquad = lane >> 4;
  const int colbase = wid * 96;

  s16x8 afrag[4];
  #pragma unroll
  for (int ks = 0; ks < 4; ++ks) {
    const int koff = ks * 32 + lquad * 8;
    const float4 p0 = *reinterpret_cast<const float4*>(&hpad[lrow][koff]);
    const float4 p1 = *reinterpret_cast<const float4*>(&hpad[lrow][koff + 4]);
    s16x8 af;
    af[0] = (short)f2bf(p0.x); af[1] = (short)f2bf(p0.y);
    af[2] = (short)f2bf(p0.z); af[3] = (short)f2bf(p0.w);
    af[4] = (short)f2bf(p1.x); af[5] = (short)f2bf(p1.y);
    af[6] = (short)f2bf(p1.z); af[7] = (short)f2bf(p1.w);
    afrag[ks] = af;
  }

  f32x4 acc[6];
  #pragma unroll
  for (int tt = 0; tt < 6; ++tt) acc[tt] = (f32x4){0.f, 0.f, 0.f, 0.f};

  #pragma unroll
  for (int tt = 0; tt < 6; ++tt) {
    const int cg2 = colbase + tt * 16 + lrow;
    #pragma unroll
    for (int ks = 0; ks < 4; ++ks) {
      const s16x8 bf = *reinterpret_cast<const s16x8*>(
          &wTq[(size_t)cg2 * 128 + ks * 32 + lquad * 8]);
      acc[tt] = __builtin_amdgcn_mfma_f32_16x16x32_bf16(afrag[ks], bf, acc[tt], 0, 0, 0);
    }
  }

  #pragma unroll
  for (int tt = 0; tt < 6; ++tt) {
    const int cg2 = colbase + tt * 16 + lrow;
    const float bz = bias[cg2];
    const int hj = cg2 / 24;
    const int off = cg2 - hj * 24;
    int moff;
    if (off < 8)       moff = hj * 8 + off;
    else if (off < 16) moff = 128 + (hj * 8 + off - 8) * 2;
    else               moff = 128 + (hj * 8 + off - 16) * 2 + 1;
    #pragma unroll
    for (int r = 0; r < 4; ++r)
      so[lquad * 4 + r][moff] = acc[tt][r] + bz;
  }
  __syncthreads();

  #pragma unroll
  for (int kk = 0; kk < 4; ++kk) {
    const int i = tid + kk * 256;
    const int rowi = i >> 6;
    const int c2 = i & 63;
    qb[(size_t)(a0 + rowi) * 64 + c2] =
        packbf(so[rowi][2 * c2], so[rowi][2 * c2 + 1]);
  }
  #pragma unroll
  for (int kk = 0; kk < 8; ++kk) {
    const int i = tid + kk * 256;
    const int rowi = i >> 7;
    const int c = i & 127;
    kvb[(size_t)(a0 + rowi) * 128 + c] =
        packbf(so[rowi][128 + 2 * c], so[rowi][128 + 2 * c + 1]);
  }
}

// ---------------------------------------------------------------------------
// K2: edge accumulation (R8/R13 structure — best measured). 1 atom/wave, 4
// waves/block, 2 ch/lane. Quad (4-edge) A/B software pipeline: data for quad
// q issued 2 quads before consumption (8 edges in flight), descriptors
// fetched 1 quad ahead on the scalar path (uniform indices). Tails via index
// clamp + scalar masks. No atomics.
// ---------------------------------------------------------------------------
__global__ __launch_bounds__(256) void k_edge_csr(
    const unsigned* __restrict__ qb, const uint2* __restrict__ kvb,
    const float2* __restrict__ ef2, const int4* __restrict__ descA,
    const float2* __restrict__ descB, const int* __restrict__ base,
    unsigned* __restrict__ mfeatw, float* __restrict__ outvec)
{
  const int tid = threadIdx.x;
  const int a = blockIdx.x * 4 + (tid >> 6);
  const int t = tid & 63;

  const int pBeg = __builtin_amdgcn_readfirstlane(base[a]);
  const int pEnd = __builtin_amdgcn_readfirstlane(base[a + 1]);

  float f0 = 0.f, f1 = 0.f;
  float va0 = 0.f, va1 = 0.f, vb0 = 0.f, vb1 = 0.f, vc0 = 0.f, vc1 = 0.f;

  if (pBeg < pEnd) {
    const unsigned qp = qb[(size_t)a * 64 + t];
    const float q0 = bflo(qp), q1 = bfhi(qp);
    const int pEnd_ = pEnd, pLast = pEnd - 1;

    int4 u0, u1, u2, u3;
    float2 w0, w1, w2, w3;
    uint2 kvA0, kvA1, kvA2, kvA3, kvB0, kvB1, kvB2, kvB3;
    float2 efA0, efA1, efA2, efA3, efB0, efB1, efB2, efB3;
    float rA0, rA1, rA2, rA3, xA0, xA1, xA2, xA3;
    float yA0, yA1, yA2, yA3, zA0, zA1, zA2, zA3;
    float rB0, rB1, rB2, rB3, xB0, xB1, xB2, xB3;
    float yB0, yB1, yB2, yB3, zB0, zB1, zB2, zB3;

#define LOAD_DESC(P) do {                                                   \
    const int j0_ = ((P)     <= pLast) ? (P)     : pLast;                   \
    const int j1_ = ((P) + 1 <= pLast) ? (P) + 1 : pLast;                   \
    const int j2_ = ((P) + 2 <= pLast) ? (P) + 2 : pLast;                   \
    const int j3_ = ((P) + 3 <= pLast) ? (P) + 3 : pLast;                   \
    u0 = descA[j0_]; w0 = descB[j0_];                                       \
    u1 = descA[j1_]; w1 = descB[j1_];                                       \
    u2 = descA[j2_]; w2 = descB[j2_];                                       \
    u3 = descA[j3_]; w3 = descB[j3_];                                       \
  } while (0)

#define COPY_PAY(S) do {                                                    \
    r##S##0 = __int_as_float(u0.z); x##S##0 = __int_as_float(u0.w);         \
    y##S##0 = w0.x; z##S##0 = w0.y;                                         \
    r##S##1 = __int_as_float(u1.z); x##S##1 = __int_as_float(u1.w);         \
    y##S##1 = w1.x; z##S##1 = w1.y;                                         \
    r##S##2 = __int_as_float(u2.z); x##S##2 = __int_as_float(u2.w);         \
    y##S##2 = w2.x; z##S##2 = w2.y;                                         \
    r##S##3 = __int_as_float(u3.z); x##S##3 = __int_as_float(u3.w);         \
    y##S##3 = w3.x; z##S##3 = w3.y;                                         \
  } while (0)

#define ISSUE_DATA(S) do {                                                  \
    kv##S##0 = kvb[(size_t)(unsigned)u0.y * 64 + t];                        \
    ef##S##0 = ef2[(size_t)(unsigned)u0.x * 64 + t];                        \
    kv##S##1 = kvb[(size_t)(unsigned)u1.y * 64 + t];                        \
    ef##S##1 = ef2[(size_t)(unsigned)u1.x * 64 + t];                        \
    kv##S##2 = kvb[(size_t)(unsigned)u2.y * 64 + t];                        \
    ef##S##2 = ef2[(size_t)(unsigned)u2.x * 64 + t];                        \
    kv##S##3 = kvb[(size_t)(unsigned)u3.y * 64 + t];                        \
    ef##S##3 = ef2[(size_t)(unsigned)u3.x * 64 + t];                        \
  } while (0)

#define EDGE1(KV, EF, RR, XX, YY, ZZ, MM) do {                              \
    const float kx0_ = bflo(KV.x), kx1_ = bflo(KV.y);                       \
    const float vx0_ = bfhi(KV.x) * (MM), vx1_ = bfhi(KV.y) * (MM);         \
    float pd_ = q0 * kx0_; pd_ = fmaf(q1, kx1_, pd_);                       \
    pd_ += __shfl_xor(pd_, 1); pd_ += __shfl_xor(pd_, 2);                   \
    const float at_ = gelu_fast(pd_) * (RR);                                \
    f0 = fmaf(vx0_ * EF.x, at_, f0);                                        \
    f1 = fmaf(vx1_ * EF.y, at_, f1);                                        \
    va0 = fmaf(vx0_, (XX), va0); va1 = fmaf(vx1_, (XX), va1);               \
    vb0 = fmaf(vx0_, (YY), vb0); vb1 = fmaf(vx1_, (YY), vb1);               \
    vc0 = fmaf(vx0_, (ZZ), vc0); vc1 = fmaf(vx1_, (ZZ), vc1);               \
  } while (0)

#define COMPUTE(S, P) do {                                                  \
    const float m1_ = ((P) + 1 < pEnd_) ? 1.f : 0.f;                        \
    const float m2_ = ((P) + 2 < pEnd_) ? 1.f : 0.f;                        \
    const float m3_ = ((P) + 3 < pEnd_) ? 1.f : 0.f;                        \
    EDGE1(kv##S##0, ef##S##0, r##S##0, x##S##0, y##S##0, z##S##0, 1.f);     \
    EDGE1(kv##S##1, ef##S##1, r##S##1, x##S##1, y##S##1, z##S##1, m1_);     \
    EDGE1(kv##S##2, ef##S##2, r##S##2, x##S##2, y##S##2, z##S##2, m2_);     \
    EDGE1(kv##S##3, ef##S##3, r##S##3, x##S##3, y##S##3, z##S##3, m3_);     \
  } while (0)

    // prologue: fill A (quad 0), B (quad 1); U = desc(quad 2)
    LOAD_DESC(pBeg);
    COPY_PAY(A); ISSUE_DATA(A);
    LOAD_DESC(pBeg + 4);
    COPY_PAY(B); ISSUE_DATA(B);
    LOAD_DESC(pBeg + 8);

    int p = pBeg;
    while (true) {
      COMPUTE(A, p);
      p += 4; if (p >= pEnd_) break;
      COPY_PAY(A); ISSUE_DATA(A);   // quad p+4 (from U = desc of old p+8)
      LOAD_DESC(p + 8);             // desc for next reload
      COMPUTE(B, p);
      p += 4; if (p >= pEnd_) break;
      COPY_PAY(B); ISSUE_DATA(B);
      LOAD_DESC(p + 8);
    }

#undef LOAD_DESC
#undef COPY_PAY
#undef ISSUE_DATA
#undef EDGE1
#undef COMPUTE
  }

  mfeatw[(size_t)a * 64 + t] = packbf(f0, f1);
  float* ov = outvec + (size_t)a * 384 + 2 * t;
  *reinterpret_cast<float2*>(ov)       = make_float2(va0, va1);
  *reinterpret_cast<float2*>(ov + 128) = make_float2(vb0, vb1);
  *reinterpret_cast<float2*>(ov + 256) = make_float2(vc0, vc1);
}

// ---------------------------------------------------------------------------
// K3: delta_node_feat = m_feat(bf16) @ out_wT(bf16) + out_b via MFMA,
// LDS-staged coalesced epilogue.
// ---------------------------------------------------------------------------
__global__ __launch_bounds__(256) void k_out(
    const unsigned short* __restrict__ mfeatb,
    const unsigned short* __restrict__ wTo,
    const float* __restrict__ bias, float* __restrict__ out)
{
  __shared__ float so[16][132];
  const int a0 = blockIdx.x * 16;
  const int tid = threadIdx.x;
  const int wid = tid >> 6;
  const int lane = tid & 63;
  const int lrow = lane & 15;
  const int lquad = lane >> 4;

  s16x8 afrag[4];
  #pragma unroll
  for (int ks = 0; ks < 4; ++ks)
    afrag[ks] = *reinterpret_cast<const s16x8*>(
        &mfeatb[(size_t)(a0 + lrow) * 128 + ks * 32 + lquad * 8]);

  f32x4 acc[2];
  acc[0] = (f32x4){0.f, 0.f, 0.f, 0.f};
  acc[1] = (f32x4){0.f, 0.f, 0.f, 0.f};

  #pragma unroll
  for (int tt = 0; tt < 2; ++tt) {
    const int cg2 = wid * 32 + tt * 16 + lrow;
    #pragma unroll
    for (int ks = 0; ks < 4; ++ks) {
      const s16x8 bf = *reinterpret_cast<const s16x8*>(
          &wTo[(size_t)cg2 * 128 + ks * 32 + lquad * 8]);
      acc[tt] = __builtin_amdgcn_mfma_f32_16x16x32_bf16(afrag[ks], bf, acc[tt], 0, 0, 0);
    }
  }

  #pragma unroll
  for (int tt = 0; tt < 2; ++tt) {
    const int cg2 = wid * 32 + tt * 16 + lrow;
    const float bz = bias[cg2];
    #pragma unroll
    for (int r = 0; r < 4; ++r)
      so[lquad * 4 + r][cg2] = acc[tt][r] + bz;
  }
  __syncthreads();

  f32x4* out4 = (f32x4*)out;
  #pragma unroll
  for (int kk = 0; kk < 2; ++kk) {
    const int idx4 = tid + kk * 256;
    const int rowi = idx4 >> 5;
    const int c4 = idx4 & 31;
    out4[(size_t)(a0 + rowi) * 32 + c4] =
        *reinterpret_cast<const f32x4*>(&so[rowi][c4 * 4]);
  }
}

extern "C" void kernel_launch(void* const* d_in, const int* in_sizes, int n_in,
                              void* d_out, int out_size, void* d_ws, size_t ws_size,
                              hipStream_t stream) {
  const float* node_feat = (const float*)d_in[0];
  const float* edge_feat = (const float*)d_in[1];
  const float* edge_vec  = (const float*)d_in[2];
  const float* radial    = (const float*)d_in[3];
  const float* qkv_w     = (const float*)d_in[4];
  const float* qkv_b     = (const float*)d_in[5];
  const float* out_w     = (const float*)d_in[6];
  const float* out_b     = (const float*)d_in[7];
  const float* ln_g      = (const float*)d_in[8];
  const float* ln_b      = (const float*)d_in[9];
  const int*   row       = (const int*)d_in[10];
  const int*   col       = (const int*)d_in[11];

  float* out      = (float*)d_out;
  float* out_feat = out;                           // [50000][128]
  float* out_vec  = out + (size_t)NATOMS * DIM;    // [50000][3][128]

  // workspace layout (16B-aligned sections)
  unsigned* qb  = (unsigned*)d_ws;                              // 50000*64 u32
  unsigned* kvb = qb + (size_t)NATOMS * 64;                     // 50000*128 u32
  unsigned short* mfeatb = (unsigned short*)(kvb + (size_t)NATOMS * 128); // 50000*128 bf16
  unsigned short* wTq = mfeatb + (size_t)NATOMS * 128;          // 384*128 bf16
  unsigned short* wTo = wTq + 384 * 128;                        // 128*128 bf16
  int4* descA  = (int4*)(wTo + 128 * 128);                      // 400000 int4
  float2* descB = (float2*)(descA + NEDGES);                    // 400000 float2
  int* cnt    = (int*)(descB + NEDGES);                         // 50000
  int* base   = cnt + NATOMS;                                   // 50001
  int* cursor = base + NATOMS + 1;                              // 50000
  int* locx   = cursor + NATOMS;                                // 50000
  int* psum   = locx + NATOMS;                                  // 256

  k_prep<<<256, 256, 0, stream>>>(qkv_w, out_w, wTq, wTo, cnt);

  // cooperative fused CSR build (hist + scan1 + scan23)
  {
    const int4* row4 = (const int4*)row;
    void* args[] = {(void*)&row4, (void*)&cnt, (void*)&locx,
                    (void*)&psum, (void*)&base, (void*)&cursor};
    hipLaunchCooperativeKernel((void*)k_csr_build, dim3(SCAN_NB), dim3(256),
                               args, 0, stream);
  }

  k_scatter_ln<<<SCAT_NB + LN_NB, 256, 0, stream>>>(
      row, col, radial, edge_vec, cursor, descA, descB,
      node_feat, wTq, qkv_b, ln_g, ln_b, qb, kvb);

  k_edge_csr<<<NATOMS / 4, 256, 0, stream>>>(
      qb, (const uint2*)kvb, (const float2*)edge_feat, descA, descB, base,
      (unsigned*)mfeatb, out_vec);

  k_out<<<NATOMS / 16, 256, 0, stream>>>(mfeatb, wTo, out_b, out_feat);
}

// Round 17
// 198.956 us; speedup vs baseline: 1.2614x; 1.2614x over previous
//
#include <hip/hip_runtime.h>
#include <math.h>

#define DIM 128
#define NHEADS 16
#define DPH 8
#define NATOMS 50000
#define NEDGES 400000
#define LN_EPS 1e-5f

typedef float f32x4 __attribute__((ext_vector_type(4)));
typedef short s16x8 __attribute__((ext_vector_type(8)));

static __device__ __forceinline__ unsigned short f2bf(float f) {
  unsigned u = __builtin_bit_cast(unsigned, f);
  unsigned r = (u + 0x7FFFu + ((u >> 16) & 1u)) >> 16;  // RNE
  return (unsigned short)r;
}
static __device__ __forceinline__ unsigned packbf(float lo, float hi) {
  return (unsigned)f2bf(lo) | ((unsigned)f2bf(hi) << 16);
}
static __device__ __forceinline__ float bflo(unsigned u) {
  return __builtin_bit_cast(float, u << 16);
}
static __device__ __forceinline__ float bfhi(unsigned u) {
  return __builtin_bit_cast(float, u & 0xffff0000u);
}

// fast GELU (tanh form): x * sigmoid(2*c0*(x + c1*x^3))
static __device__ __forceinline__ float gelu_fast(float x) {
  const float c0 = 0.7978845608028654f;
  const float c1 = 0.044715f;
  float u = c0 * (x + c1 * x * x * x);
  return __fdividef(x, 1.0f + __expf(-2.0f * u));
}

#define HIST4_NB ((NEDGES / 4 + 255) / 256)  // 391
#define SCAT_NB ((NEDGES + 255) / 256)       // 1563
#define SCAN_NB 196                          // ceil(50000/256)
#define LN_NB (NATOMS / 16)                  // 3125

// ---------------------------------------------------------------------------
// k_prep: weight convert/transpose + cnt zeroing (256 blocks x 256 = 65536
// threads covers 49152 wTq + 16384 wTo and 50000 cnt).
// ---------------------------------------------------------------------------
__global__ __launch_bounds__(256) void k_prep(
    const float* __restrict__ qkv_w, const float* __restrict__ out_w,
    unsigned short* __restrict__ wTq, unsigned short* __restrict__ wTo,
    int* __restrict__ cnt)
{
  const int idx = blockIdx.x * 256 + threadIdx.x;
  if (idx < NATOMS) cnt[idx] = 0;
  if (idx < 384 * 128) {
    const int c = idx >> 7, k = idx & 127;
    wTq[idx] = f2bf(qkv_w[k * 384 + c]);
  } else {
    const int i2 = idx - 384 * 128;
    const int c = i2 >> 7, k = i2 & 127;
    wTo[i2] = f2bf(out_w[k * 128 + c]);
  }
}

// ---------------------------------------------------------------------------
// k_hist4: row histogram, int4-vectorized (4 edges/thread).
// ---------------------------------------------------------------------------
__global__ __launch_bounds__(256) void k_hist4(const int4* __restrict__ row4,
                                               int* __restrict__ cnt)
{
  const int e4 = blockIdx.x * 256 + threadIdx.x;
  if (e4 < NEDGES / 4) {
    const int4 r = row4[e4];
    atomicAdd(&cnt[r.x], 1);
    atomicAdd(&cnt[r.y], 1);
    atomicAdd(&cnt[r.z], 1);
    atomicAdd(&cnt[r.w], 1);
  }
}

// ---------------------------------------------------------------------------
// CSR scan: per-block scan -> (offset-from-psum + apply)
// ---------------------------------------------------------------------------
__global__ __launch_bounds__(256) void k_scan1(const int* __restrict__ cnt,
                                               int* __restrict__ locx,
                                               int* __restrict__ psum) {
  __shared__ int sh[256];
  const int tid = threadIdx.x;
  const int i = blockIdx.x * 256 + tid;
  const int v = (i < NATOMS) ? cnt[i] : 0;
  sh[tid] = v;
  __syncthreads();
  #pragma unroll
  for (int off = 1; off < 256; off <<= 1) {
    const int cur = sh[tid];
    const int add = (tid >= off) ? sh[tid - off] : 0;
    __syncthreads();
    sh[tid] = cur + add;
    __syncthreads();
  }
  if (i < NATOMS) locx[i] = sh[tid] - v;  // exclusive
  if (tid == 255) psum[blockIdx.x] = sh[255];
}

__global__ __launch_bounds__(256) void k_scan23(const int* __restrict__ psum,
                                                const int* __restrict__ locx,
                                                int* __restrict__ base,
                                                int* __restrict__ cursor) {
  __shared__ int ws[4];
  const int bid = blockIdx.x;
  const int tid = threadIdx.x;
  const int lane = tid & 63;
  const int wid = tid >> 6;

  int s = (tid < bid) ? psum[tid] : 0;  // bid <= 195 < 256
  #pragma unroll
  for (int m = 1; m < 64; m <<= 1) s += __shfl_xor(s, m);
  if (lane == 0) ws[wid] = s;
  __syncthreads();
  const int off = ws[0] + ws[1] + ws[2] + ws[3];

  const int i = bid * 256 + tid;
  if (i < NATOMS) {
    const int b = locx[i] + off;
    base[i] = b;
    cursor[i] = b;
  }
  if (bid == 0 && tid == 0) base[NATOMS] = NEDGES;
}

// ---------------------------------------------------------------------------
// k_scatter_ln: FUSED grid. Blocks [0, SCAT_NB): scatter edge descriptors
// into CSR order (descA[p]={e,col,radial,ev0}, descB[p]={ev1,ev2}). Blocks
// [SCAT_NB, SCAT_NB+LN_NB): LayerNorm + QKV projection (MFMA), packed bf16
// outputs. The two workloads are independent (scatter needs cursor; LN needs
// wTq) and co-schedule across CUs — scatter's scattered-write latency hides
// under LN's MFMA/BW work, removing ~15us of serialization.
// ---------------------------------------------------------------------------
__global__ __launch_bounds__(256) void k_scatter_ln(
    const int* __restrict__ row, const int* __restrict__ col,
    const float* __restrict__ radial, const float* __restrict__ evec,
    int* __restrict__ cursor, int4* __restrict__ descA,
    float2* __restrict__ descB,
    const float* __restrict__ node, const unsigned short* __restrict__ wTq,
    const float* __restrict__ bias, const float* __restrict__ g,
    const float* __restrict__ beta, unsigned* __restrict__ qb,
    unsigned* __restrict__ kvb)
{
  if (blockIdx.x < SCAT_NB) {
    const int e = blockIdx.x * 256 + threadIdx.x;
    if (e < NEDGES) {
      const int p = atomicAdd(&cursor[row[e]], 1);
      descA[p] = make_int4(e, col[e], __float_as_int(radial[e]),
                           __float_as_int(evec[(size_t)e * 3]));
      descB[p] = make_float2(evec[(size_t)e * 3 + 1], evec[(size_t)e * 3 + 2]);
    }
    return;
  }

  __shared__ float hpad[16][132];
  __shared__ float so[16][388];
  const int a0 = (blockIdx.x - SCAT_NB) * 16;
  const int tid = threadIdx.x;
  const int wid = tid >> 6;
  const int lane = tid & 63;

  for (int j = 0; j < 4; ++j) {
    const int a = wid * 4 + j;
    const float x0 = node[(size_t)(a0 + a) * DIM + lane];
    const float x1 = node[(size_t)(a0 + a) * DIM + 64 + lane];
    float s = x0 + x1;
    #pragma unroll
    for (int m = 1; m < 64; m <<= 1) s += __shfl_xor(s, m);
    const float mu = s * (1.0f / 128.0f);
    const float d0 = x0 - mu, d1 = x1 - mu;
    float v = d0 * d0 + d1 * d1;
    #pragma unroll
    for (int m = 1; m < 64; m <<= 1) v += __shfl_xor(v, m);
    const float rs = rsqrtf(v * (1.0f / 128.0f) + LN_EPS);
    hpad[a][lane]      = d0 * rs * g[lane]      + beta[lane];
    hpad[a][64 + lane] = d1 * rs * g[64 + lane] + beta[64 + lane];
  }
  __syncthreads();

  const int lrow = lane & 15;
  const int lquad = lane >> 4;
  const int colbase = wid * 96;

  s16x8 afrag[4];
  #pragma unroll
  for (int ks = 0; ks < 4; ++ks) {
    const int koff = ks * 32 + lquad * 8;
    const float4 p0 = *reinterpret_cast<const float4*>(&hpad[lrow][koff]);
    const float4 p1 = *reinterpret_cast<const float4*>(&hpad[lrow][koff + 4]);
    s16x8 af;
    af[0] = (short)f2bf(p0.x); af[1] = (short)f2bf(p0.y);
    af[2] = (short)f2bf(p0.z); af[3] = (short)f2bf(p0.w);
    af[4] = (short)f2bf(p1.x); af[5] = (short)f2bf(p1.y);
    af[6] = (short)f2bf(p1.z); af[7] = (short)f2bf(p1.w);
    afrag[ks] = af;
  }

  f32x4 acc[6];
  #pragma unroll
  for (int tt = 0; tt < 6; ++tt) acc[tt] = (f32x4){0.f, 0.f, 0.f, 0.f};

  #pragma unroll
  for (int tt = 0; tt < 6; ++tt) {
    const int cg = colbase + tt * 16 + lrow;
    #pragma unroll
    for (int ks = 0; ks < 4; ++ks) {
      const s16x8 bf = *reinterpret_cast<const s16x8*>(
          &wTq[(size_t)cg * 128 + ks * 32 + lquad * 8]);
      acc[tt] = __builtin_amdgcn_mfma_f32_16x16x32_bf16(afrag[ks], bf, acc[tt], 0, 0, 0);
    }
  }

  #pragma unroll
  for (int tt = 0; tt < 6; ++tt) {
    const int cg = colbase + tt * 16 + lrow;
    const float bz = bias[cg];
    const int hj = cg / 24;
    const int off = cg - hj * 24;
    int moff;
    if (off < 8)       moff = hj * 8 + off;
    else if (off < 16) moff = 128 + (hj * 8 + off - 8) * 2;
    else               moff = 128 + (hj * 8 + off - 16) * 2 + 1;
    #pragma unroll
    for (int r = 0; r < 4; ++r)
      so[lquad * 4 + r][moff] = acc[tt][r] + bz;
  }
  __syncthreads();

  #pragma unroll
  for (int kk = 0; kk < 4; ++kk) {
    const int i = tid + kk * 256;
    const int rowi = i >> 6;
    const int c2 = i & 63;
    qb[(size_t)(a0 + rowi) * 64 + c2] =
        packbf(so[rowi][2 * c2], so[rowi][2 * c2 + 1]);
  }
  #pragma unroll
  for (int kk = 0; kk < 8; ++kk) {
    const int i = tid + kk * 256;
    const int rowi = i >> 7;
    const int c = i & 127;
    kvb[(size_t)(a0 + rowi) * 128 + c] =
        packbf(so[rowi][128 + 2 * c], so[rowi][128 + 2 * c + 1]);
  }
}

// ---------------------------------------------------------------------------
// K2: edge accumulation (R8/R13 structure — best measured). 1 atom/wave, 4
// waves/block, 2 ch/lane. Quad (4-edge) A/B software pipeline: data for quad
// q issued 2 quads before consumption (8 edges in flight), descriptors
// fetched 1 quad ahead on the scalar path (uniform indices). Tails via index
// clamp + scalar masks. No atomics.
// ---------------------------------------------------------------------------
__global__ __launch_bounds__(256) void k_edge_csr(
    const unsigned* __restrict__ qb, const uint2* __restrict__ kvb,
    const float2* __restrict__ ef2, const int4* __restrict__ descA,
    const float2* __restrict__ descB, const int* __restrict__ base,
    unsigned* __restrict__ mfeatw, float* __restrict__ outvec)
{
  const int tid = threadIdx.x;
  const int a = blockIdx.x * 4 + (tid >> 6);
  const int t = tid & 63;

  const int pBeg = __builtin_amdgcn_readfirstlane(base[a]);
  const int pEnd = __builtin_amdgcn_readfirstlane(base[a + 1]);

  float f0 = 0.f, f1 = 0.f;
  float va0 = 0.f, va1 = 0.f, vb0 = 0.f, vb1 = 0.f, vc0 = 0.f, vc1 = 0.f;

  if (pBeg < pEnd) {
    const unsigned qp = qb[(size_t)a * 64 + t];
    const float q0 = bflo(qp), q1 = bfhi(qp);
    const int pEnd_ = pEnd, pLast = pEnd - 1;

    int4 u0, u1, u2, u3;
    float2 w0, w1, w2, w3;
    uint2 kvA0, kvA1, kvA2, kvA3, kvB0, kvB1, kvB2, kvB3;
    float2 efA0, efA1, efA2, efA3, efB0, efB1, efB2, efB3;
    float rA0, rA1, rA2, rA3, xA0, xA1, xA2, xA3;
    float yA0, yA1, yA2, yA3, zA0, zA1, zA2, zA3;
    float rB0, rB1, rB2, rB3, xB0, xB1, xB2, xB3;
    float yB0, yB1, yB2, yB3, zB0, zB1, zB2, zB3;

#define LOAD_DESC(P) do {                                                   \
    const int j0_ = ((P)     <= pLast) ? (P)     : pLast;                   \
    const int j1_ = ((P) + 1 <= pLast) ? (P) + 1 : pLast;                   \
    const int j2_ = ((P) + 2 <= pLast) ? (P) + 2 : pLast;                   \
    const int j3_ = ((P) + 3 <= pLast) ? (P) + 3 : pLast;                   \
    u0 = descA[j0_]; w0 = descB[j0_];                                       \
    u1 = descA[j1_]; w1 = descB[j1_];                                       \
    u2 = descA[j2_]; w2 = descB[j2_];                                       \
    u3 = descA[j3_]; w3 = descB[j3_];                                       \
  } while (0)

#define COPY_PAY(S) do {                                                    \
    r##S##0 = __int_as_float(u0.z); x##S##0 = __int_as_float(u0.w);         \
    y##S##0 = w0.x; z##S##0 = w0.y;                                         \
    r##S##1 = __int_as_float(u1.z); x##S##1 = __int_as_float(u1.w);         \
    y##S##1 = w1.x; z##S##1 = w1.y;                                         \
    r##S##2 = __int_as_float(u2.z); x##S##2 = __int_as_float(u2.w);         \
    y##S##2 = w2.x; z##S##2 = w2.y;                                         \
    r##S##3 = __int_as_float(u3.z); x##S##3 = __int_as_float(u3.w);         \
    y##S##3 = w3.x; z##S##3 = w3.y;                                         \
  } while (0)

#define ISSUE_DATA(S) do {                                                  \
    kv##S##0 = kvb[(size_t)(unsigned)u0.y * 64 + t];                        \
    ef##S##0 = ef2[(size_t)(unsigned)u0.x * 64 + t];                        \
    kv##S##1 = kvb[(size_t)(unsigned)u1.y * 64 + t];                        \
    ef##S##1 = ef2[(size_t)(unsigned)u1.x * 64 + t];                        \
    kv##S##2 = kvb[(size_t)(unsigned)u2.y * 64 + t];                        \
    ef##S##2 = ef2[(size_t)(unsigned)u2.x * 64 + t];                        \
    kv##S##3 = kvb[(size_t)(unsigned)u3.y * 64 + t];                        \
    ef##S##3 = ef2[(size_t)(unsigned)u3.x * 64 + t];                        \
  } while (0)

#define EDGE1(KV, EF, RR, XX, YY, ZZ, MM) do {                              \
    const float kx0_ = bflo(KV.x), kx1_ = bflo(KV.y);                       \
    const float vx0_ = bfhi(KV.x) * (MM), vx1_ = bfhi(KV.y) * (MM);         \
    float pd_ = q0 * kx0_; pd_ = fmaf(q1, kx1_, pd_);                       \
    pd_ += __shfl_xor(pd_, 1); pd_ += __shfl_xor(pd_, 2);                   \
    const float at_ = gelu_fast(pd_) * (RR);                                \
    f0 = fmaf(vx0_ * EF.x, at_, f0);                                        \
    f1 = fmaf(vx1_ * EF.y, at_, f1);                                        \
    va0 = fmaf(vx0_, (XX), va0); va1 = fmaf(vx1_, (XX), va1);               \
    vb0 = fmaf(vx0_, (YY), vb0); vb1 = fmaf(vx1_, (YY), vb1);               \
    vc0 = fmaf(vx0_, (ZZ), vc0); vc1 = fmaf(vx1_, (ZZ), vc1);               \
  } while (0)

#define COMPUTE(S, P) do {                                                  \
    const float m1_ = ((P) + 1 < pEnd_) ? 1.f : 0.f;                        \
    const float m2_ = ((P) + 2 < pEnd_) ? 1.f : 0.f;                        \
    const float m3_ = ((P) + 3 < pEnd_) ? 1.f : 0.f;                        \
    EDGE1(kv##S##0, ef##S##0, r##S##0, x##S##0, y##S##0, z##S##0, 1.f);     \
    EDGE1(kv##S##1, ef##S##1, r##S##1, x##S##1, y##S##1, z##S##1, m1_);     \
    EDGE1(kv##S##2, ef##S##2, r##S##2, x##S##2, y##S##2, z##S##2, m2_);     \
    EDGE1(kv##S##3, ef##S##3, r##S##3, x##S##3, y##S##3, z##S##3, m3_);     \
  } while (0)

    // prologue: fill A (quad 0), B (quad 1); U = desc(quad 2)
    LOAD_DESC(pBeg);
    COPY_PAY(A); ISSUE_DATA(A);
    LOAD_DESC(pBeg + 4);
    COPY_PAY(B); ISSUE_DATA(B);
    LOAD_DESC(pBeg + 8);

    int p = pBeg;
    while (true) {
      COMPUTE(A, p);
      p += 4; if (p >= pEnd_) break;
      COPY_PAY(A); ISSUE_DATA(A);   // quad p+4 (from U = desc of old p+8)
      LOAD_DESC(p + 8);             // desc for next reload
      COMPUTE(B, p);
      p += 4; if (p >= pEnd_) break;
      COPY_PAY(B); ISSUE_DATA(B);
      LOAD_DESC(p + 8);
    }

#undef LOAD_DESC
#undef COPY_PAY
#undef ISSUE_DATA
#undef EDGE1
#undef COMPUTE
  }

  mfeatw[(size_t)a * 64 + t] = packbf(f0, f1);
  float* ov = outvec + (size_t)a * 384 + 2 * t;
  *reinterpret_cast<float2*>(ov)       = make_float2(va0, va1);
  *reinterpret_cast<float2*>(ov + 128) = make_float2(vb0, vb1);
  *reinterpret_cast<float2*>(ov + 256) = make_float2(vc0, vc1);
}

// ---------------------------------------------------------------------------
// K3: delta_node_feat = m_feat(bf16) @ out_wT(bf16) + out_b via MFMA,
// LDS-staged coalesced epilogue.
// ---------------------------------------------------------------------------
__global__ __launch_bounds__(256) void k_out(
    const unsigned short* __restrict__ mfeatb,
    const unsigned short* __restrict__ wTo,
    const float* __restrict__ bias, float* __restrict__ out)
{
  __shared__ float so[16][132];
  const int a0 = blockIdx.x * 16;
  const int tid = threadIdx.x;
  const int wid = tid >> 6;
  const int lane = tid & 63;
  const int lrow = lane & 15;
  const int lquad = lane >> 4;

  s16x8 afrag[4];
  #pragma unroll
  for (int ks = 0; ks < 4; ++ks)
    afrag[ks] = *reinterpret_cast<const s16x8*>(
        &mfeatb[(size_t)(a0 + lrow) * 128 + ks * 32 + lquad * 8]);

  f32x4 acc[2];
  acc[0] = (f32x4){0.f, 0.f, 0.f, 0.f};
  acc[1] = (f32x4){0.f, 0.f, 0.f, 0.f};

  #pragma unroll
  for (int tt = 0; tt < 2; ++tt) {
    const int cg = wid * 32 + tt * 16 + lrow;
    #pragma unroll
    for (int ks = 0; ks < 4; ++ks) {
      const s16x8 bf = *reinterpret_cast<const s16x8*>(
          &wTo[(size_t)cg * 128 + ks * 32 + lquad * 8]);
      acc[tt] = __builtin_amdgcn_mfma_f32_16x16x32_bf16(afrag[ks], bf, acc[tt], 0, 0, 0);
    }
  }

  #pragma unroll
  for (int tt = 0; tt < 2; ++tt) {
    const int cg = wid * 32 + tt * 16 + lrow;
    const float bz = bias[cg];
    #pragma unroll
    for (int r = 0; r < 4; ++r)
      so[lquad * 4 + r][cg] = acc[tt][r] + bz;
  }
  __syncthreads();

  f32x4* out4 = (f32x4*)out;
  #pragma unroll
  for (int kk = 0; kk < 2; ++kk) {
    const int idx4 = tid + kk * 256;
    const int rowi = idx4 >> 5;
    const int c4 = idx4 & 31;
    out4[(size_t)(a0 + rowi) * 32 + c4] =
        *reinterpret_cast<const f32x4*>(&so[rowi][c4 * 4]);
  }
}

extern "C" void kernel_launch(void* const* d_in, const int* in_sizes, int n_in,
                              void* d_out, int out_size, void* d_ws, size_t ws_size,
                              hipStream_t stream) {
  const float* node_feat = (const float*)d_in[0];
  const float* edge_feat = (const float*)d_in[1];
  const float* edge_vec  = (const float*)d_in[2];
  const float* radial    = (const float*)d_in[3];
  const float* qkv_w     = (const float*)d_in[4];
  const float* qkv_b     = (const float*)d_in[5];
  const float* out_w     = (const float*)d_in[6];
  const float* out_b     = (const float*)d_in[7];
  const float* ln_g      = (const float*)d_in[8];
  const float* ln_b      = (const float*)d_in[9];
  const int*   row       = (const int*)d_in[10];
  const int*   col       = (const int*)d_in[11];

  float* out      = (float*)d_out;
  float* out_feat = out;                           // [50000][128]
  float* out_vec  = out + (size_t)NATOMS * DIM;    // [50000][3][128]

  // workspace layout (16B-aligned sections)
  unsigned* qb  = (unsigned*)d_ws;                              // 50000*64 u32
  unsigned* kvb = qb + (size_t)NATOMS * 64;                     // 50000*128 u32
  unsigned short* mfeatb = (unsigned short*)(kvb + (size_t)NATOMS * 128); // 50000*128 bf16
  unsigned short* wTq = mfeatb + (size_t)NATOMS * 128;          // 384*128 bf16
  unsigned short* wTo = wTq + 384 * 128;                        // 128*128 bf16
  int4* descA  = (int4*)(wTo + 128 * 128);                      // 400000 int4
  float2* descB = (float2*)(descA + NEDGES);                    // 400000 float2
  int* cnt    = (int*)(descB + NEDGES);                         // 50000
  int* base   = cnt + NATOMS;                                   // 50001
  int* cursor = base + NATOMS + 1;                              // 50000
  int* locx   = cursor + NATOMS;                                // 50000
  int* psum   = locx + NATOMS;                                  // 256

  k_prep<<<256, 256, 0, stream>>>(qkv_w, out_w, wTq, wTo, cnt);

  k_hist4<<<HIST4_NB, 256, 0, stream>>>((const int4*)row, cnt);

  k_scan1<<<SCAN_NB, 256, 0, stream>>>(cnt, locx, psum);
  k_scan23<<<SCAN_NB, 256, 0, stream>>>(psum, locx, base, cursor);

  k_scatter_ln<<<SCAT_NB + LN_NB, 256, 0, stream>>>(
      row, col, radial, edge_vec, cursor, descA, descB,
      node_feat, wTq, qkv_b, ln_g, ln_b, qb, kvb);

  k_edge_csr<<<NATOMS / 4, 256, 0, stream>>>(
      qb, (const uint2*)kvb, (const float2*)edge_feat, descA, descB, base,
      (unsigned*)mfeatb, out_vec);

  k_out<<<NATOMS / 16, 256, 0, stream>>>(mfeatb, wTo, out_b, out_feat);
}